// Round 1
// 116.433 us; speedup vs baseline: 1.0989x; 1.0989x over previous
//
#include <hip/hip_runtime.h>
#include <math.h>

#define N_NODES 1024
#define N_EVAL 131072
#define NUM_POLES 8
#define PI_D 3.14159265358979323846

// ============================================================================
// V2: two-kernel design.
//
// Old kernel was latency-bound (VALUBusy 21%, dur 73.5us vs ~7us trans-pipe
// roofline): wave-uniform node data was streamed through LDS ds_read_b128
// broadcasts with an exposed ~120cy lgkmcnt stall per 4-node group (VGPR=36
// shows the unroll-4 never materialized), at only 16 waves/CU.
//
// Fix: node coefficient stream is wave-uniform -> move it to the SCALAR path.
//  - setup_kernel: closed-form barycentric weights (fp64, computed ONCE, not
//    per block) into d_ws: ws[0..1024)=nodes, [1024..2048)=w, [2048..3072)=w*v.
//  - eval_scalar_kernel: 2048 blocks x 256 thr (8 waves/EU = 100% occupancy).
//    Each block: 64 points; wave w handles nodes [w*256, w*256+256) for all
//    64 points (1 point/thread). Node/w/v loads have wave-uniform addresses
//    (wid via readfirstlane) -> compiler emits s_load into SGPRs; inner loop
//    is pure VALU: v_subrev(d = x - s_n), v_rcp, 2x v_fma with SGPR operands.
//    No LDS / no barrier / no lgkmcnt dependency in the hot loop.
//    4 wave-partials per point reduced through a 2KB LDS buffer, then divide;
//    rare exact-hit (NaN) fix-up rescans nodes from ws (reference semantics:
//    exact-hit column reduces to sum(hit w*v)/sum(hit w)).
// ============================================================================

__global__ __launch_bounds__(256) void setup_kernel(
    const float* __restrict__ values,
    const float* __restrict__ poles_real,
    const float* __restrict__ poles_imag,
    float* __restrict__ ws) {
    const int j = blockIdx.x * 256 + threadIdx.x;
    // Chebyshev node (2nd kind), fp64 for node accuracy near the ends.
    const double nd = cos(PI_D * (double)j / (double)(N_NODES - 1));
    // 1/prod_{i!=j}(x_j-x_i) = (-1)^j * delta_j * 2^(n-1)/n ; uniform positive
    // scalings cancel in num/den, so keep only (-1)^j * delta_j * pole products.
    double prod = (j == 0 || j == N_NODES - 1) ? 0.5 : 1.0;
#pragma unroll
    for (int m = 0; m < NUM_POLES; ++m) {
        const double dr = nd - (double)poles_real[m];
        const double di = (double)poles_imag[m];
        prod *= dr * dr + di * di;
    }
    if (j & 1) prod = -prod;
    ws[j]        = (float)nd;
    ws[j + 1024] = (float)prod;
    ws[j + 2048] = (float)(prod * (double)values[j]);
}

__global__ __launch_bounds__(256, 8) void eval_scalar_kernel(
    const float* __restrict__ x_eval,
    const float* __restrict__ ws,
    float* __restrict__ out) {
    __shared__ float2 s_red[4][64];

    const int t = threadIdx.x;
    const int lane = t & 63;
    // Force wave-uniformity so the node-stream addresses scalarize (s_load).
    const int wid = __builtin_amdgcn_readfirstlane(t >> 6);
    const int pbase = blockIdx.x * 64;

    const float x = x_eval[pbase + lane];

    const float* __restrict__ nn = ws + wid * 256;
    const float* __restrict__ wq = ws + 1024 + wid * 256;
    const float* __restrict__ vq = ws + 2048 + wid * 256;

    // Two independent accumulator chains per (num,den) for FMA-latency cover.
    float a0 = 0.0f, b0 = 0.0f, a1 = 0.0f, b1 = 0.0f;

#pragma unroll 2
    for (int j = 0; j < 256; j += 8) {
#pragma unroll
        for (int k = 0; k < 8; k += 2) {
            const float n0 = nn[j + k];
            const float w0 = wq[j + k];
            const float v0 = vq[j + k];
            const float n1 = nn[j + k + 1];
            const float w1 = wq[j + k + 1];
            const float v1 = vq[j + k + 1];
            const float d0 = x - n0;
            const float d1 = x - n1;
            const float r0 = __builtin_amdgcn_rcpf(d0);
            const float r1 = __builtin_amdgcn_rcpf(d1);
            a0 = fmaf(v0, r0, a0);
            b0 = fmaf(w0, r0, b0);
            a1 = fmaf(v1, r1, a1);
            b1 = fmaf(w1, r1, b1);
        }
    }

    s_red[wid][lane] = make_float2(a0 + a1, b0 + b1);
    __syncthreads();

    if (t < 64) {
        float num = 0.0f, den = 0.0f;
#pragma unroll
        for (int w = 0; w < 4; ++w) {
            const float2 p = s_red[w][t];
            num += p.x;
            den += p.y;
        }
        float res = num / den;
        if (__builtin_expect(__builtin_isnan(res), 0)) {
            const float xx = x_eval[pbase + t];
            float hn = 0.0f, hd = 0.0f;
            for (int jj = 0; jj < N_NODES; ++jj) {
                if (ws[jj] == xx) { hn += ws[2048 + jj]; hd += ws[1024 + jj]; }
            }
            res = hn / hd;
        }
        out[pbase + t] = res;
    }
}

// ============================================================================
// Fallback (previous verified kernel) if the harness workspace is too small.
// ============================================================================
__global__ __launch_bounds__(512, 4) void eval_kernel_fused(
    const float* __restrict__ x_eval,
    const float* __restrict__ values,
    const float* __restrict__ poles_real,
    const float* __restrict__ poles_imag,
    float* __restrict__ out) {
    __shared__ __align__(16) float s_n[N_NODES];
    __shared__ __align__(16) float s_w[N_NODES];
    __shared__ __align__(16) float s_v[N_NODES];
    __shared__ float2 s_r[8][256];

    const int t = threadIdx.x;

#pragma unroll
    for (int h = 0; h < 2; ++h) {
        const int j = t + h * 512;
        const double nd = cos(PI_D * (double)j / (double)(N_NODES - 1));
        double prod = (j == 0 || j == N_NODES - 1) ? 0.5 : 1.0;
#pragma unroll
        for (int m = 0; m < NUM_POLES; ++m) {
            const double dr = nd - (double)poles_real[m];
            const double di = (double)poles_imag[m];
            prod *= dr * dr + di * di;
        }
        if (j & 1) prod = -prod;
        s_n[j] = (float)nd;
        s_w[j] = (float)prod;
        s_v[j] = (float)(prod * (double)values[j]);
    }
    __syncthreads();

    const int lane = t & 63;
    const int wid  = t >> 6;
    const int pbase = blockIdx.x * 256;
    const float x0 = x_eval[pbase + lane];
    const float x1 = x_eval[pbase + 64 + lane];
    const float x2 = x_eval[pbase + 128 + lane];
    const float x3 = x_eval[pbase + 192 + lane];

    const float4* n4 = (const float4*)s_n + wid * 32;
    const float4* w4 = (const float4*)s_w + wid * 32;
    const float4* v4 = (const float4*)s_v + wid * 32;

    float a0 = 0.0f, b0 = 0.0f, a1 = 0.0f, b1 = 0.0f;
    float a2 = 0.0f, b2 = 0.0f, a3 = 0.0f, b3 = 0.0f;

#define NODE(C)                                                            \
    {                                                                      \
        const float d0 = x0 - an.C;                                        \
        const float d1 = x1 - an.C;                                        \
        const float d2 = x2 - an.C;                                        \
        const float d3 = x3 - an.C;                                        \
        const float r0 = __builtin_amdgcn_rcpf(d0);                        \
        const float r1 = __builtin_amdgcn_rcpf(d1);                        \
        const float r2 = __builtin_amdgcn_rcpf(d2);                        \
        const float r3 = __builtin_amdgcn_rcpf(d3);                        \
        a0 = fmaf(av.C, r0, a0); b0 = fmaf(aw.C, r0, b0);                  \
        a1 = fmaf(av.C, r1, a1); b1 = fmaf(aw.C, r1, b1);                  \
        a2 = fmaf(av.C, r2, a2); b2 = fmaf(aw.C, r2, b2);                  \
        a3 = fmaf(av.C, r3, a3); b3 = fmaf(aw.C, r3, b3);                  \
    }

#pragma unroll 4
    for (int q = 0; q < 32; ++q) {
        const float4 an = n4[q];
        const float4 aw = w4[q];
        const float4 av = v4[q];
        NODE(x) NODE(y) NODE(z) NODE(w)
    }
#undef NODE

    s_r[wid][lane]       = make_float2(a0, b0);
    s_r[wid][lane + 64]  = make_float2(a1, b1);
    s_r[wid][lane + 128] = make_float2(a2, b2);
    s_r[wid][lane + 192] = make_float2(a3, b3);
    __syncthreads();

    if (t < 256) {
        float nn = 0.0f, dd = 0.0f;
#pragma unroll
        for (int w = 0; w < 8; ++w) {
            const float2 pr = s_r[w][t];
            nn += pr.x;
            dd += pr.y;
        }
        float res = nn / dd;
        if (__builtin_expect(__builtin_isnan(res), 0)) {
            const float x = x_eval[pbase + t];
            float hn = 0.0f, hd = 0.0f;
            for (int j = 0; j < N_NODES; ++j) {
                if (s_n[j] == x) { hn += s_v[j]; hd += s_w[j]; }
            }
            res = hn / hd;
        }
        out[pbase + t] = res;
    }
}

extern "C" void kernel_launch(void* const* d_in, const int* in_sizes, int n_in,
                              void* d_out, int out_size, void* d_ws, size_t ws_size,
                              hipStream_t stream) {
    const float* x_eval     = (const float*)d_in[0];
    const float* values     = (const float*)d_in[1];
    const float* poles_real = (const float*)d_in[2];
    const float* poles_imag = (const float*)d_in[3];
    float* out = (float*)d_out;

    if (ws_size >= 3 * N_NODES * sizeof(float)) {
        float* ws = (float*)d_ws;
        setup_kernel<<<N_NODES / 256, 256, 0, stream>>>(values, poles_real,
                                                        poles_imag, ws);
        eval_scalar_kernel<<<N_EVAL / 64, 256, 0, stream>>>(x_eval, ws, out);
    } else {
        eval_kernel_fused<<<N_EVAL / 256, 512, 0, stream>>>(
            x_eval, values, poles_real, poles_imag, out);
    }
}